// Round 5
// baseline (233.794 us; speedup 1.0000x reference)
//
#include <hip/hip_runtime.h>
#include <math.h>

// Problem constants
#define HH 2048
#define EE 64
#define TOPK 8
#define NT 16384
#define MT 32            // tokens per WG
#define KC 16            // K elems per chunk (one 32x32x16 MFMA k-step)
#define KQR 512          // K range per K-quarter
#define NCH 32           // KQR / KC
#define LS 68            // slog row stride (floats)

typedef __attribute__((ext_vector_type(8)))  short short8;  // 8 bf16 (4 VGPRs)
typedef __attribute__((ext_vector_type(16))) float f32x16;  // 32x32 MFMA acc

// 3-limb bf16 split: v = h + m + l + eps, |eps| <= 2^-25 |v|.
// (identical to the round-3/4 harness-passing version)
static __device__ __forceinline__ void cvt3(const float4& a, const float4& b,
                                            short8& h, short8& m, short8& l)
{
    const float v[8] = {a.x, a.y, a.z, a.w, b.x, b.y, b.z, b.w};
#pragma unroll
    for (int i = 0; i < 8; ++i) {
        const unsigned int u = __float_as_uint(v[i]);
        h[i] = (short)(u >> 16);
        const float r1 = v[i] - __uint_as_float(u & 0xffff0000u);
        const unsigned int u1 = __float_as_uint(r1);
        m[i] = (short)(u1 >> 16);
        const float r2 = r1 - __uint_as_float(u1 & 0xffff0000u);
        const unsigned int u2 = __float_as_uint(r2);
        l[i] = (short)((u2 + 0x7fffu + ((u2 >> 16) & 1u)) >> 16);
    }
}

// ---------------- Pre-kernel: W -> fragment-ready 3-limb bf16 ----------------
// Layout: [eb][kq][c][limb p][lane][8 shorts]; lane = l5*32 + lr encodes
// (expert row lr, k-octet l5) exactly as the MFMA B-fragment wants it, so the
// main kernel's W load is 3 fully-coalesced 1KB dwordx4 loads per chunk.
// Total 768 KB (L2-resident).
__global__ __launch_bounds__(256) void wsplit(
    const float* __restrict__ w, short* __restrict__ wsw)
{
    const int e = blockIdx.x;        // expert 0..63
    const int o = threadIdx.x;       // k-octet 0..255
    const int k = o * 8;
    const float4 a = *(const float4*)(w + (size_t)e * HH + k);
    const float4 b = *(const float4*)(w + (size_t)e * HH + k + 4);
    short8 h, m, l;
    cvt3(a, b, h, m, l);

    const int eb = e >> 5, lr = e & 31;
    const int kq = k >> 9;
    const int c  = (k >> 4) & 31;
    const int l5 = (k >> 3) & 1;
    const int lane = l5 * 32 + lr;
    short* dst = wsw + ((size_t)(((eb * 4 + kq) * 32 + c) * 3) * 64 + lane) * 8;
    *(short8*)(dst)            = h;   // p=0 at +0
    *(short8*)(dst + 64 * 8)   = m;   // p=1 at +512 shorts
    *(short8*)(dst + 128 * 8)  = l;   // p=2 at +1024 shorts
}

// ---------------- Main kernel ----------------
// 512 threads = 8 waves = 2 expert-halves (eb) x 4 K-quarters (kq), MT=32
// tokens. Grid 512 -> 2 blocks/CU -> 4 waves/SIMD. Per-wave acc = one eb
// (32 VGPR), 2-deep register pipeline; total ~104 VGPR fits the 128 cap of
// __launch_bounds__(512,4) without spill.
__global__ __launch_bounds__(512, 4) void router_fused(
    const float* __restrict__ x,          // [NT, H] fp32
    const short* __restrict__ wsw,        // fragment-ready W limbs
    float* __restrict__ out_logits,
    float* __restrict__ out_wts,
    float* __restrict__ out_idx)
{
    __shared__ float slog[MT * LS];       // 8.7 KB; epilogue only

    const int t    = threadIdx.x;
    const int wv   = t >> 6;
    const int lane = t & 63;
    const int eb   = wv & 1;              // expert half (32 cols)
    const int kq   = wv >> 1;             // K-quarter 0..3
    const int l5   = lane >> 5;           // k-octet within 16-k chunk
    const int lr   = lane & 31;           // token row (A) / expert col (B)
    const int tok0 = blockIdx.x * MT;

    // A source: lane lr = token, 32B contiguous per lane.
    const float* xp = x + (size_t)(tok0 + lr) * HH + kq * KQR + l5 * 8;
    // B source: fragment-ready, coalesced (lane*8 shorts).
    const short* wbase = wsw + ((size_t)((eb * 4 + kq) * 32) * 192 + lane) * 8;
    // per chunk stride: 3 limbs * 64 lanes * 8 = 1536 shorts

    f32x16 accM = {0}, accS = {0};

    short8 wA[3], wB[3];
    float4 xa0, xa1, xb0, xb1;

    auto wload = [&](short8* bw, int c) {
        const short* p0 = wbase + (size_t)c * 1536;
        bw[0] = *(const short8*)(p0);             // h
        bw[1] = *(const short8*)(p0 + 512);       // m
        bw[2] = *(const short8*)(p0 + 1024);      // l
    };
    auto xload = [&](float4& a, float4& b, int c) {
        a = *(const float4*)(xp + c * KC);
        b = *(const float4*)(xp + c * KC + 4);
    };
    auto compute = [&](const float4& a, const float4& b, const short8* bw) {
        short8 xh, xm, xl;
        cvt3(a, b, xh, xm, xl);
        accM = __builtin_amdgcn_mfma_f32_32x32x16_bf16(xh, bw[0], accM, 0, 0, 0);
        accS = __builtin_amdgcn_mfma_f32_32x32x16_bf16(xh, bw[1], accS, 0, 0, 0);
        accS = __builtin_amdgcn_mfma_f32_32x32x16_bf16(xm, bw[0], accS, 0, 0, 0);
        accS = __builtin_amdgcn_mfma_f32_32x32x16_bf16(xh, bw[2], accS, 0, 0, 0);
        accS = __builtin_amdgcn_mfma_f32_32x32x16_bf16(xl, bw[0], accS, 0, 0, 0);
        accS = __builtin_amdgcn_mfma_f32_32x32x16_bf16(xm, bw[1], accS, 0, 0, 0);
    };

    // prologue: fill both pipeline slots
    wload(wA, 0); xload(xa0, xa1, 0);
    wload(wB, 1); xload(xb0, xb1, 1);

#pragma unroll 1
    for (int c = 0; c < NCH; c += 2) {
        compute(xa0, xa1, wA);
        if (c + 2 < NCH) { wload(wA, c + 2); xload(xa0, xa1, c + 2); }
        compute(xb0, xb1, wB);
        if (c + 3 < NCH) { wload(wB, c + 3); xload(xb0, xb1, c + 3); }
    }

    // ---- K-quarter reduction into slog ----
    // 32x32 C/D layout (m74/m101): col = lane&31, row = (r&3)+8*(r>>2)+4*(l>>5)
    const int col = eb * 32 + lr;
#pragma unroll 1
    for (int q = 0; q < 4; ++q) {
        if (kq == q) {
#pragma unroll
            for (int r = 0; r < 16; ++r) {
                const int row = (r & 3) + 8 * (r >> 2) + 4 * l5;
                const float val = accM[r] + accS[r];
                if (q == 0) slog[row * LS + col] = val;
                else        slog[row * LS + col] += val;
            }
        }
        __syncthreads();
    }

    // ---- coalesced logits write: 32 tokens x 64 experts, 512 threads ----
    {
        const int row = t >> 4;           // 0..31
        const int c4  = (t & 15) * 4;
        const float4 o0 = *(const float4*)&slog[row * LS + c4];
        *(float4*)(out_logits + (size_t)(tok0 + row) * EE + c4) = o0;
    }

    // ---- top-8 + softmax: one lane per token (harness-proven code) ----
    if (t < MT) {
        float tv[TOPK];
        int   ti[TOPK];
#pragma unroll
        for (int q = 0; q < TOPK; ++q) { tv[q] = -INFINITY; ti[q] = 0; }

        for (int e = 0; e < EE; ++e) {
            const float val = slog[t * LS + e];
            if (val > tv[TOPK - 1]) {
                tv[TOPK - 1] = val;
                ti[TOPK - 1] = e;
#pragma unroll
                for (int q = TOPK - 1; q > 0; --q) {
                    if (tv[q] > tv[q - 1]) {   // strict: lowest-index-first on ties
                        float fv = tv[q]; tv[q] = tv[q - 1]; tv[q - 1] = fv;
                        int   fi = ti[q]; ti[q] = ti[q - 1]; ti[q - 1] = fi;
                    }
                }
            }
        }

        const float m = tv[0];
        float ew[TOPK];
        float sum = 0.f;
#pragma unroll
        for (int q = 0; q < TOPK; ++q) { ew[q] = expf(tv[q] - m); sum += ew[q]; }
        const float inv = 1.f / sum;

        const size_t tok = (size_t)(tok0 + t);
        float4 w0, w1, i0, i1;
        w0.x = ew[0] * inv; w0.y = ew[1] * inv; w0.z = ew[2] * inv; w0.w = ew[3] * inv;
        w1.x = ew[4] * inv; w1.y = ew[5] * inv; w1.z = ew[6] * inv; w1.w = ew[7] * inv;
        i0.x = (float)ti[0]; i0.y = (float)ti[1]; i0.z = (float)ti[2]; i0.w = (float)ti[3];
        i1.x = (float)ti[4]; i1.y = (float)ti[5]; i1.z = (float)ti[6]; i1.w = (float)ti[7];
        *(float4*)(out_wts + tok * TOPK)     = w0;
        *(float4*)(out_wts + tok * TOPK + 4) = w1;
        *(float4*)(out_idx + tok * TOPK)     = i0;
        *(float4*)(out_idx + tok * TOPK + 4) = i1;
    }
}

extern "C" void kernel_launch(void* const* d_in, const int* in_sizes, int n_in,
                              void* d_out, int out_size, void* d_ws, size_t ws_size,
                              hipStream_t stream) {
    const float* x = (const float*)d_in[0];   // hidden_states [4,4096,2048] fp32
    const float* w = (const float*)d_in[1];   // gate_w [64,2048] fp32
    float* out        = (float*)d_out;
    float* out_logits = out;                               // 16384*64
    float* out_wts    = out + (size_t)NT * EE;             // 16384*8
    float* out_idx    = out_wts + (size_t)NT * TOPK;       // 16384*8
    short* wsw = (short*)d_ws;                             // 768 KB limb planes

    hipLaunchKernelGGL(wsplit, dim3(EE), dim3(256), 0, stream, w, wsw);
    hipLaunchKernelGGL(router_fused, dim3(NT / MT), dim3(512), 0, stream,
                       x, wsw, out_logits, out_wts, out_idx);
}

// Round 7
// 219.845 us; speedup vs baseline: 1.0634x; 1.0634x over previous
//
#include <hip/hip_runtime.h>
#include <math.h>

// Problem constants
#define HH 2048
#define EE 64
#define TOPK 8
#define NT 16384
#define MT 32            // tokens per WG
#define KC 128           // K elems per chunk (tile: 32 tokens x 128 k)
#define NCH 16           // HH / KC
#define LS 68            // slog row stride (floats)

typedef __attribute__((ext_vector_type(8)))  short short8;  // 8 bf16 (4 VGPRs)
typedef __attribute__((ext_vector_type(16))) float f32x16;  // 32x32 MFMA acc

// 3-limb bf16 split: v = h + m + l + eps, |eps| <= 2^-25 |v|.
// (identical to the round-3/4/5 harness-passing version)
static __device__ __forceinline__ void cvt3(const float4& a, const float4& b,
                                            short8& h, short8& m, short8& l)
{
    const float v[8] = {a.x, a.y, a.z, a.w, b.x, b.y, b.z, b.w};
#pragma unroll
    for (int i = 0; i < 8; ++i) {
        const unsigned int u = __float_as_uint(v[i]);
        h[i] = (short)(u >> 16);
        const float r1 = v[i] - __uint_as_float(u & 0xffff0000u);
        const unsigned int u1 = __float_as_uint(r1);
        m[i] = (short)(u1 >> 16);
        const float r2 = r1 - __uint_as_float(u1 & 0xffff0000u);
        const unsigned int u2 = __float_as_uint(r2);
        l[i] = (short)((u2 + 0x7fffu + ((u2 >> 16) & 1u)) >> 16);
    }
}

// ---------------- Pre-kernel: W -> fragment-ready 3-limb bf16 ----------------
// Layout: [eb][s16][limb p][lane][8 shorts], s16 = global 16-k-step (0..127),
// lane = l5*32 + (e&31) = exact MFMA B-fragment order. Main-kernel B load =
// 3 fully-coalesced 1KB dwordx4 loads per k-step. Total 768 KB, L2-resident.
__global__ __launch_bounds__(256) void wsplit(
    const float* __restrict__ w, short* __restrict__ wsw)
{
    const int e = blockIdx.x;        // expert 0..63
    const int o = threadIdx.x;       // k-octet 0..255
    const int k = o * 8;
    const float4 a = *(const float4*)(w + (size_t)e * HH + k);
    const float4 b = *(const float4*)(w + (size_t)e * HH + k + 4);
    short8 h, m, l;
    cvt3(a, b, h, m, l);

    const int eb  = e >> 5, lr = e & 31;
    const int s16 = o >> 1;          // 16-k-step index
    const int l5  = o & 1;           // k-octet within step
    const int lane = l5 * 32 + lr;
    short* dst = wsw + (((size_t)(eb * 128 + s16) * 3) * 64 + lane) * 8;
    *(short8*)(dst)           = h;   // p=0
    *(short8*)(dst + 64 * 8)  = m;   // p=1
    *(short8*)(dst + 128 * 8) = l;   // p=2
}

// ---------------- Main kernel ----------------
// 512 threads = 8 waves = 2 expert-halves (eb) x 4 in-chunk K-quarters (kq).
// Staging threads read x coalesced (512B bursts/row), cvt3 ONCE, and write
// fragment-ready bf16 limb tiles to LDS (XOR-swizzled). Compute waves'
// inner loop is pure ds_read_b128 + coalesced L2 B-loads + MFMA (no VALU).
// LDS 48 KB double-buffered -> 2 blocks/CU at __launch_bounds__(512,4).
__global__ __launch_bounds__(512, 4) void router_fused(
    const float* __restrict__ x,          // [NT, H] fp32
    const short* __restrict__ wsw,        // fragment-ready W limbs
    float* __restrict__ out_logits,
    float* __restrict__ out_wts,
    float* __restrict__ out_idx)
{
    // [buf][ (s16l*3+p)*64 + swizzled lane ] short8 units; 2*1536*16B = 48 KB
    __shared__ __align__(16) short8 xsl[2][1536];
    float* slog = (float*)xsl;            // epilogue overlay

    const int t    = threadIdx.x;
    const int wv   = t >> 6;
    const int lane = t & 63;
    const int eb   = wv & 1;              // expert half (32 cols)
    const int kq   = wv >> 1;             // in-chunk K-quarter (2 k-steps)
    const int l5   = lane >> 5;           // k-octet within 16-k step
    const int lr   = lane & 31;           // token row (A) / expert col (B)
    const int tok0 = blockIdx.x * MT;

    // staging role: thread owns (row sr, k-octet su) of the 32x128 tile
    const int sr = t >> 4;                // 0..31
    const int su = t & 15;                // octet 0..15
    const float* xg = x + (size_t)(tok0 + sr) * HH + su * 8;
    const int s16s = su >> 1;             // staging k-step within chunk
    const int lfs  = (su & 1) * 32 + sr;  // fragment lane this octet feeds

    f32x16 accM = {0}, accS = {0};
    float4 xr0, xr1;

    auto sload = [&](int c) {
        xr0 = *(const float4*)(xg + (size_t)c * KC);
        xr1 = *(const float4*)(xg + (size_t)c * KC + 4);
    };
    auto swrite = [&](int buf) {
        short8 h, m, l;
        cvt3(xr0, xr1, h, m, l);
        const int b0 = s16s * 3;
        xsl[buf][((b0 + 0) << 6) + (lfs ^ ((b0 + 0) & 7))] = h;
        xsl[buf][((b0 + 1) << 6) + (lfs ^ ((b0 + 1) & 7))] = m;
        xsl[buf][((b0 + 2) << 6) + (lfs ^ ((b0 + 2) & 7))] = l;
    };
    auto chunk = [&](int c, int buf) {
#pragma unroll
        for (int st = 0; st < 2; ++st) {
            const int s16l = kq * 2 + st;          // step within chunk 0..7
            const int s16g = c * 8 + s16l;         // global step 0..127
            const short8* wp = (const short8*)wsw
                             + ((size_t)(eb * 128 + s16g) * 3) * 64 + lane;
            const short8 B0 = wp[0];
            const short8 B1 = wp[64];
            const short8 B2 = wp[128];
            const int ab = s16l * 3;
            const short8 Ah = xsl[buf][((ab + 0) << 6) + (lane ^ ((ab + 0) & 7))];
            const short8 Am = xsl[buf][((ab + 1) << 6) + (lane ^ ((ab + 1) & 7))];
            const short8 Al = xsl[buf][((ab + 2) << 6) + (lane ^ ((ab + 2) & 7))];
            accM = __builtin_amdgcn_mfma_f32_32x32x16_bf16(Ah, B0, accM, 0, 0, 0);
            accS = __builtin_amdgcn_mfma_f32_32x32x16_bf16(Ah, B1, accS, 0, 0, 0);
            accS = __builtin_amdgcn_mfma_f32_32x32x16_bf16(Am, B0, accS, 0, 0, 0);
            accS = __builtin_amdgcn_mfma_f32_32x32x16_bf16(Ah, B2, accS, 0, 0, 0);
            accS = __builtin_amdgcn_mfma_f32_32x32x16_bf16(Al, B0, accS, 0, 0, 0);
            accS = __builtin_amdgcn_mfma_f32_32x32x16_bf16(Am, B1, accS, 0, 0, 0);
        }
    };

    // prologue: stage chunk 0
    sload(0);
    swrite(0);
    __syncthreads();

#pragma unroll 1
    for (int c = 0; c < NCH; ++c) {
        if (c + 1 < NCH) sload(c + 1);     // issue next burst early
        chunk(c, c & 1);                   // compute current buffer
        if (c + 1 < NCH) swrite((c + 1) & 1);
        __syncthreads();
    }
    // final barrier also guards the slog overlay below

    // ---- K-quarter reduction into slog ----
    // 32x32 C/D layout (m74/m101): col = lane&31, row = (r&3)+8*(r>>2)+4*(l>>5)
    const int col = eb * 32 + lr;
#pragma unroll 1
    for (int q = 0; q < 4; ++q) {
        if (kq == q) {
#pragma unroll
            for (int r = 0; r < 16; ++r) {
                const int row = (r & 3) + 8 * (r >> 2) + 4 * l5;
                const float val = accM[r] + accS[r];
                if (q == 0) slog[row * LS + col] = val;
                else        slog[row * LS + col] += val;
            }
        }
        __syncthreads();
    }

    // ---- coalesced logits write: 32 tokens x 64 experts, 512 threads ----
    {
        const int row = t >> 4;           // 0..31
        const int c4  = (t & 15) * 4;
        const float4 o0 = *(const float4*)&slog[row * LS + c4];
        *(float4*)(out_logits + (size_t)(tok0 + row) * EE + c4) = o0;
    }

    // ---- top-8 + softmax: one lane per token (harness-proven code) ----
    if (t < MT) {
        float tv[TOPK];
        int   ti[TOPK];
#pragma unroll
        for (int q = 0; q < TOPK; ++q) { tv[q] = -INFINITY; ti[q] = 0; }

        for (int e = 0; e < EE; ++e) {
            const float val = slog[t * LS + e];
            if (val > tv[TOPK - 1]) {
                tv[TOPK - 1] = val;
                ti[TOPK - 1] = e;
#pragma unroll
                for (int q = TOPK - 1; q > 0; --q) {
                    if (tv[q] > tv[q - 1]) {   // strict: lowest-index-first on ties
                        float fv = tv[q]; tv[q] = tv[q - 1]; tv[q - 1] = fv;
                        int   fi = ti[q]; ti[q] = ti[q - 1]; ti[q - 1] = fi;
                    }
                }
            }
        }

        const float m = tv[0];
        float ew[TOPK];
        float sum = 0.f;
#pragma unroll
        for (int q = 0; q < TOPK; ++q) { ew[q] = expf(tv[q] - m); sum += ew[q]; }
        const float inv = 1.f / sum;

        const size_t tok = (size_t)(tok0 + t);
        float4 w0, w1, i0, i1;
        w0.x = ew[0] * inv; w0.y = ew[1] * inv; w0.z = ew[2] * inv; w0.w = ew[3] * inv;
        w1.x = ew[4] * inv; w1.y = ew[5] * inv; w1.z = ew[6] * inv; w1.w = ew[7] * inv;
        i0.x = (float)ti[0]; i0.y = (float)ti[1]; i0.z = (float)ti[2]; i0.w = (float)ti[3];
        i1.x = (float)ti[4]; i1.y = (float)ti[5]; i1.z = (float)ti[6]; i1.w = (float)ti[7];
        *(float4*)(out_wts + tok * TOPK)     = w0;
        *(float4*)(out_wts + tok * TOPK + 4) = w1;
        *(float4*)(out_idx + tok * TOPK)     = i0;
        *(float4*)(out_idx + tok * TOPK + 4) = i1;
    }
}

extern "C" void kernel_launch(void* const* d_in, const int* in_sizes, int n_in,
                              void* d_out, int out_size, void* d_ws, size_t ws_size,
                              hipStream_t stream) {
    const float* x = (const float*)d_in[0];   // hidden_states [4,4096,2048] fp32
    const float* w = (const float*)d_in[1];   // gate_w [64,2048] fp32
    float* out        = (float*)d_out;
    float* out_logits = out;                               // 16384*64
    float* out_wts    = out + (size_t)NT * EE;             // 16384*8
    float* out_idx    = out_wts + (size_t)NT * TOPK;       // 16384*8
    short* wsw = (short*)d_ws;                             // 768 KB limb planes

    hipLaunchKernelGGL(wsplit, dim3(EE), dim3(256), 0, stream, w, wsw);
    hipLaunchKernelGGL(router_fused, dim3(NT / MT), dim3(512), 0, stream,
                       x, wsw, out_logits, out_wts, out_idx);
}